// Round 14
// baseline (2109.746 us; speedup 1.0000x reference)
//
#include <hip/hip_runtime.h>
#include <math.h>

#define B_ 64
#define T_ 48
#define H_ 512
#define V_ 32000
#define G_ 2048
#define BH_ (B_*H_)
#define BG_ (B_*G_)

typedef short short8 __attribute__((ext_vector_type(8)));
typedef float f32x4 __attribute__((ext_vector_type(4)));

__device__ __forceinline__ float sigmoidf_(float x){ return 1.f/(1.f+__expf(-x)); }

__device__ __forceinline__ unsigned short f2bf(float f){
  unsigned u = __float_as_uint(f);
  u += 0x7fffu + ((u>>16)&1u);
  return (unsigned short)(u>>16);
}
__device__ __forceinline__ float bf2f(unsigned short u){
  return __uint_as_float(((unsigned)u)<<16);
}

__device__ __forceinline__ short8 cvt8(const float* g){
  float4 a = *(const float4*)g;
  float4 b = *(const float4*)(g+4);
  short8 v;
  v[0]=(short)f2bf(a.x); v[1]=(short)f2bf(a.y); v[2]=(short)f2bf(a.z); v[3]=(short)f2bf(a.w);
  v[4]=(short)f2bf(b.x); v[5]=(short)f2bf(b.y); v[6]=(short)f2bf(b.z); v[7]=(short)f2bf(b.w);
  return v;
}

// ---------------------------------------------------------------------------
// prep: all weight conversions + bias sums + state/flag init, one launch
// ---------------------------------------------------------------------------
__global__ void prep_kernel(
    const float* __restrict__ w_hh1, const float* __restrict__ w_hhd1,
    const float* __restrict__ w_hh2, const float* __restrict__ w_ih2,
    const float* __restrict__ w_hhd2, const float* __restrict__ w_ihd2,
    const float* __restrict__ w_ih1, const float* __restrict__ w_o,
    const float* __restrict__ b_ihd1, const float* __restrict__ b_hhd1,
    const float* __restrict__ b_ih2,  const float* __restrict__ b_hh2,
    unsigned short* w1e, unsigned short* w1d, unsigned short* w2e, unsigned short* w2d,
    unsigned short* wx1, unsigned short* wcap, unsigned short* wo_bf,
    float* bd1s, float* b2es,
    unsigned short* h1_0, unsigned short* h2_0, unsigned* flags)
{
  const int b = blockIdx.x, t = threadIdx.x;
  if (b < 64){
    for (long i = b*256+t; i < 2048L*64; i += 64L*256){ int r=(int)(i>>6), k=(int)(i&63)*8;
      *(short8*)(w1e + (long)r*512 + k) = cvt8(w_hh1 + (long)r*512 + k); }
  } else if (b < 128){
    for (long i = (b-64)*256+t; i < 2048L*64; i += 64L*256){ int r=(int)(i>>6), k=(int)(i&63)*8;
      *(short8*)(w1d + (long)r*512 + k) = cvt8(w_hhd1 + (long)r*512 + k); }
  } else if (b < 256){
    for (long i = (b-128)*256+t; i < 2048L*128; i += 128L*256){ int r=(int)(i>>7), k=(int)(i&127)*8;
      short8 v = (k<512)? cvt8(w_hh2+(long)r*512+k) : cvt8(w_ih2+(long)r*1024+512+(k-512));
      *(short8*)(w2e + (long)r*1024 + k) = v; }
  } else if (b < 384){
    for (long i = (b-256)*256+t; i < 2048L*128; i += 128L*256){ int r=(int)(i>>7), k=(int)(i&127)*8;
      short8 v = (k<512)? cvt8(w_hhd2+(long)r*512+k) : cvt8(w_ihd2+(long)r*1024+512+(k-512));
      *(short8*)(w2d + (long)r*1024 + k) = v; }
  } else if (b < 448){
    for (long i = (b-384)*256+t; i < 2048L*64; i += 64L*256){ int r=(int)(i>>6), k=(int)(i&63)*8;
      *(short8*)(wx1 + (long)r*512 + k) = cvt8(w_ih1 + (long)r*512 + k); }
  } else if (b < 512){
    for (long i = (b-448)*256+t; i < 2048L*64; i += 64L*256){ int r=(int)(i>>6), k=(int)(i&63)*8;
      *(short8*)(wcap + (long)r*512 + k) = cvt8(w_ihd2 + (long)r*1024 + k); }
  } else if (b < 1012){
    for (long i = (long)(b-512)*256+t; i < 32000L*64; i += 500L*256){ int r=(int)(i>>6), k=(int)(i&63)*8;
      *(short8*)(wo_bf + (long)r*512 + k) = cvt8(w_o + (long)r*512 + k); }
  } else if (b < 1020){
    int n = (b-1012)*256 + t;
    bd1s[n] = b_ihd1[n] + b_hhd1[n];
    b2es[n] = b_ih2[n] + b_hh2[n];
  } else {
    short8 z = {0,0,0,0,0,0,0,0};
    for (int i=(b-1020)*256+t; i<4096; i+=4*256){ ((short8*)h1_0)[i]=z; ((short8*)h2_0)[i]=z; }
    for (int i=(b-1020)*256+t; i<4096; i+=4*256) flags[i] = 0u;
  }
}

// ---------------------------------------------------------------------------
// mm_pre2: fused X1 (s<48, from feat) and capQ (s>=48, from caption), bf16 out
// ---------------------------------------------------------------------------
__global__ __launch_bounds__(512,1) void mm_pre2_kernel(
    const float* __restrict__ feat, const float* __restrict__ caption,
    const unsigned short* __restrict__ wx1, const unsigned short* __restrict__ wcap,
    const float* __restrict__ b_ih1, const float* __restrict__ b_hh1,
    const float* __restrict__ b_ihd2, const float* __restrict__ b_hhd2,
    unsigned short* __restrict__ x1b, unsigned short* __restrict__ capqb)
{
  const int s = blockIdx.x, n0 = blockIdx.y*256;
  const int t = threadIdx.x, w = t>>6, l = t&63, ln = l&15, lk = l>>4;
  __shared__ short8 smA[64*64];
  __shared__ short8 smB[256*8];

  const float* af32; const unsigned short* Wbf; const float* bA; const float* bB;
  unsigned short* out;
  if (s < 48){ af32 = feat + (long)s*H_;          Wbf = wx1;  bA = b_ih1;  bB = b_hh1;  out = x1b  + (long)s*BG_; }
  else       { af32 = caption + (long)(s-48)*H_;  Wbf = wcap; bA = b_ihd2; bB = b_hhd2; out = capqb + (long)(s-48)*BG_; }

  f32x4 acc[4][2];
#pragma unroll
  for (int mf=0; mf<4; ++mf)
#pragma unroll
    for (int nf=0; nf<2; ++nf) acc[mf][nf] = (f32x4){0.f,0.f,0.f,0.f};

#pragma unroll
  for (int i=0;i<8;++i){ int e=i*4096+t*8; int m=e>>9, k=e&511;
    smA[m*64 + ((k>>3)^(m&7))] = cvt8(&af32[(long)m*(T_*H_) + k]); }

  for (int kc=0; kc<8; ++kc){
    __syncthreads();
#pragma unroll
    for (int i=0;i<4;++i){ int e=i*4096+t*8; int n=e>>6, k=e&63;
      smB[n*8 + ((k>>3)^(n&7))] = *(const short8*)(Wbf + (long)(n0+n)*512 + kc*64 + k); }
    __syncthreads();
#pragma unroll
    for (int ks2=0; ks2<2; ++ks2){
#pragma unroll
      for (int nf=0; nf<2; ++nf){
        int n = w*32 + nf*16 + ln;
        short8 bfr = smB[n*8 + ((ks2*4+lk)^(n&7))];
#pragma unroll
        for (int mf=0; mf<4; ++mf){
          int m = mf*16+ln;
          short8 afr = smA[m*64 + (((kc*2+ks2)*4+lk)^(m&7))];
          acc[mf][nf] = __builtin_amdgcn_mfma_f32_16x16x32_bf16(afr, bfr, acc[mf][nf], 0,0,0);
        }
      }
    }
  }
#pragma unroll
  for (int nf=0; nf<2; ++nf){
    int n = n0 + w*32 + nf*16 + ln;
    float bias = bA[n] + bB[n];
#pragma unroll
    for (int mf=0; mf<4; ++mf)
#pragma unroll
      for (int r=0; r<4; ++r){
        int m = mf*16 + lk*4 + r;
        out[(long)m*G_ + n] = f2bf(acc[mf][nf][r] + bias);
      }
  }
}

// ---------------------------------------------------------------------------
// chain: 32 blocks, BOTH layers per block per step (r10 merged structure,
// validated). One all-to-all fence-free barrier over 32 participants/step.
// h exchange: relaxed agent u64 atomic stores; __syncthreads drains vmcnt.
// ---------------------------------------------------------------------------
__global__ __launch_bounds__(256,1) void chain_kernel(
    const unsigned short* __restrict__ w1e, const unsigned short* __restrict__ w1d,
    const unsigned short* __restrict__ w2e, const unsigned short* __restrict__ w2d,
    const unsigned short* __restrict__ x1b, const unsigned short* __restrict__ capqb,
    const float* __restrict__ bd1s, const float* __restrict__ b2es,
    unsigned short* __restrict__ h1, unsigned short* __restrict__ h2,
    unsigned* __restrict__ flags)
{
  __shared__ short8 smA[64*128];        // 128 KB
  __shared__ float gbuf[4][16][68];
  __shared__ float c1_lds[16][68];
  __shared__ float c2_lds[16][68];
  const int cb = blockIdx.x;
  const int t = threadIdx.x;
  const int wv = t>>6, l = t&63, ln = l&15, lk = l>>4;
  unsigned short* stash = (unsigned short*)&smA[0];

  short8 W1e_[16], W1d_[16], W2_[32];   // 256 VGPRs resident weights
  const int col = wv*512 + cb*16 + ln;
  {
    const long wr1 = (long)col * 512;
#pragma unroll
    for (int ks=0; ks<16; ++ks){
      W1e_[ks] = *(const short8*)(w1e + wr1 + ks*32 + lk*8);
      W1d_[ks] = *(const short8*)(w1d + wr1 + ks*32 + lk*8);
    }
    const long wr2 = (long)col * 1024;
#pragma unroll
    for (int ks=0; ks<32; ++ks)
      W2_[ks] = *(const short8*)(w2e + wr2 + ks*32 + lk*8);
  }
  const float b1d = bd1s[col], b2e = b2es[col];

  for (int i=t; i<16*68; i+=256){ (&c1_lds[0][0])[i] = 0.f; (&c2_lds[0][0])[i] = 0.f; }
  __syncthreads();

  for (int u=0; u<96; ++u){
    if (u == 49){
      const long wr2 = (long)col * 1024;
#pragma unroll
      for (int ks=0; ks<32; ++ks)
        W2_[ks] = *(const short8*)(w2d + wr2 + ks*32 + lk*8);
    }
    const int L1a = (u<=94), L2a = (u>=1);

    // prev prefetch (independent of h)
    float prev1[4][4], prev2[4][4];
    if (L1a){
      if (u < 48){
        const unsigned short* pp = x1b + (long)u*BG_ + col;
#pragma unroll
        for (int mf=0;mf<4;++mf)
#pragma unroll
          for (int r=0;r<4;++r) prev1[mf][r] = bf2f(pp[(long)(mf*16+lk*4+r)*G_]);
      } else {
#pragma unroll
        for (int mf=0;mf<4;++mf)
#pragma unroll
          for (int r=0;r<4;++r) prev1[mf][r] = b1d;
      }
    }
    if (L2a){
      if (u-1 < 48){
#pragma unroll
        for (int mf=0;mf<4;++mf)
#pragma unroll
          for (int r=0;r<4;++r) prev2[mf][r] = b2e;
      } else {
        const unsigned short* pp = capqb + (long)(u-1-48)*BG_ + col;
#pragma unroll
        for (int mf=0;mf<4;++mf)
#pragma unroll
          for (int r=0;r<4;++r) prev2[mf][r] = bf2f(pp[(long)(mf*16+lk*4+r)*G_]);
      }
    }

    // stage h1[u] (upper half) and h2[u-1] (lower half)
    { const unsigned short* hpB = h1 + (long)u*BH_;
#pragma unroll
      for (int i=0;i<16;++i){ int e=i*2048+t*8; int m=e>>9, k=e&511;
        smA[m*128 + ((k>>3)^(m&7)) + 64] = *(const short8*)(hpB + m*512 + k); }
      if (L2a){
        const unsigned short* hpA = h2 + (long)(u-1)*BH_;
#pragma unroll
        for (int i=0;i<16;++i){ int e=i*2048+t*8; int m=e>>9, k=e&511;
          smA[m*128 + ((k>>3)^(m&7))] = *(const short8*)(hpA + m*512 + k); }
      }
    }
    __syncthreads();

    // both layers' MFMAs before any LDS reuse
    f32x4 acc1[4], acc2[4];
    if (L1a){
#pragma unroll
      for (int mf=0;mf<4;++mf) acc1[mf] = (f32x4){0.f,0.f,0.f,0.f};
      if (u < 48){
#pragma unroll
        for (int ks=0; ks<16; ++ks)
#pragma unroll
          for (int mf=0; mf<4; ++mf){
            int m = mf*16+ln;
            acc1[mf] = __builtin_amdgcn_mfma_f32_16x16x32_bf16(
              smA[m*128 + 64 + ((ks*4+lk)^(m&7))], W1e_[ks], acc1[mf], 0,0,0);
          }
      } else {
#pragma unroll
        for (int ks=0; ks<16; ++ks)
#pragma unroll
          for (int mf=0; mf<4; ++mf){
            int m = mf*16+ln;
            acc1[mf] = __builtin_amdgcn_mfma_f32_16x16x32_bf16(
              smA[m*128 + 64 + ((ks*4+lk)^(m&7))], W1d_[ks], acc1[mf], 0,0,0);
          }
      }
#pragma unroll
      for (int mf=0;mf<4;++mf)
#pragma unroll
        for (int r=0;r<4;++r) acc1[mf][r] += prev1[mf][r];
    }
    if (L2a){
#pragma unroll
      for (int mf=0;mf<4;++mf) acc2[mf] = (f32x4){0.f,0.f,0.f,0.f};
#pragma unroll
      for (int ks=0; ks<32; ++ks)
#pragma unroll
        for (int mf=0; mf<4; ++mf){
          int m = mf*16+ln;
          acc2[mf] = __builtin_amdgcn_mfma_f32_16x16x32_bf16(
            smA[m*128 + ((ks*4+lk)^(m&7))], W2_[ks], acc2[mf], 0,0,0);
        }
#pragma unroll
      for (int mf=0;mf<4;++mf)
#pragma unroll
        for (int r=0;r<4;++r) acc2[mf][r] += prev2[mf][r];
    }

    // ---- L1 cell ----
    if (L1a){
#pragma unroll
      for (int mf=0;mf<4;++mf) *(f32x4*)&gbuf[wv][ln][mf*16+lk*4] = acc1[mf];
    }
    __syncthreads();
    if (L1a){
      int n = t&15, m0 = (t>>4)*4;
      float4 gi = *(float4*)&gbuf[0][n][m0];
      float4 gf = *(float4*)&gbuf[1][n][m0];
      float4 gg = *(float4*)&gbuf[2][n][m0];
      float4 go = *(float4*)&gbuf[3][n][m0];
      float4 c4 = *(float4*)&c1_lds[n][m0];
      float a_i[4]={gi.x,gi.y,gi.z,gi.w}, a_f[4]={gf.x,gf.y,gf.z,gf.w};
      float a_g[4]={gg.x,gg.y,gg.z,gg.w}, a_o[4]={go.x,go.y,go.z,go.w};
      float ci[4]={c4.x,c4.y,c4.z,c4.w}, cn[4];
#pragma unroll
      for (int j=0;j<4;++j){
        float i_ = sigmoidf_(a_i[j]), f_ = sigmoidf_(a_f[j]), o_ = sigmoidf_(a_o[j]);
        float g_ = tanhf(a_g[j]);
        cn[j] = f_*ci[j] + i_*g_;
        stash[(m0+j)*24 + n] = f2bf(o_*tanhf(cn[j]));
      }
      *(float4*)&c1_lds[n][m0] = make_float4(cn[0],cn[1],cn[2],cn[3]);
    }
    __syncthreads();
    if (L1a){
      unsigned short* ho = h1 + (long)(u+1)*BH_ + cb*16;
      int m = t>>2, q = t&3;
      unsigned long long v = *(const unsigned long long*)&stash[m*24 + q*4];
      __hip_atomic_store((unsigned long long*)(ho + (long)m*512 + q*4), v,
                         __ATOMIC_RELAXED, __HIP_MEMORY_SCOPE_AGENT);
    }
    __syncthreads();   // stash reads done -> safe for L2 reuse

    // ---- L2 cell ----
    if (L2a){
#pragma unroll
      for (int mf=0;mf<4;++mf) *(f32x4*)&gbuf[wv][ln][mf*16+lk*4] = acc2[mf];
    }
    __syncthreads();
    if (L2a){
      int n = t&15, m0 = (t>>4)*4;
      float4 gi = *(float4*)&gbuf[0][n][m0];
      float4 gf = *(float4*)&gbuf[1][n][m0];
      float4 gg = *(float4*)&gbuf[2][n][m0];
      float4 go = *(float4*)&gbuf[3][n][m0];
      float4 c4 = *(float4*)&c2_lds[n][m0];
      float a_i[4]={gi.x,gi.y,gi.z,gi.w}, a_f[4]={gf.x,gf.y,gf.z,gf.w};
      float a_g[4]={gg.x,gg.y,gg.z,gg.w}, a_o[4]={go.x,go.y,go.z,go.w};
      float ci[4]={c4.x,c4.y,c4.z,c4.w}, cn[4];
#pragma unroll
      for (int j=0;j<4;++j){
        float i_ = sigmoidf_(a_i[j]), f_ = sigmoidf_(a_f[j]), o_ = sigmoidf_(a_o[j]);
        float g_ = tanhf(a_g[j]);
        cn[j] = f_*ci[j] + i_*g_;
        stash[(m0+j)*24 + n] = f2bf(o_*tanhf(cn[j]));
      }
      *(float4*)&c2_lds[n][m0] = make_float4(cn[0],cn[1],cn[2],cn[3]);
    }
    __syncthreads();
    if (L2a){
      unsigned short* ho = h2 + (long)u*BH_ + cb*16;
      int m = t>>2, q = t&3;
      unsigned long long v = *(const unsigned long long*)&stash[m*24 + q*4];
      __hip_atomic_store((unsigned long long*)(ho + (long)m*512 + q*4), v,
                         __ATOMIC_RELAXED, __HIP_MEMORY_SCOPE_AGENT);
    }

    // ---- all-to-all barrier over 32 participants ----
    if (u < 95){
      unsigned g = (unsigned)(u+1);
      __syncthreads();   // drains vmcnt: h stores at coherence point
      if (t == 0)
        __hip_atomic_store(&flags[cb*16], g, __ATOMIC_RELAXED, __HIP_MEMORY_SCOPE_AGENT);
      if (t < 32){
        while (__hip_atomic_load(&flags[t*16], __ATOMIC_RELAXED, __HIP_MEMORY_SCOPE_AGENT) < g)
          __builtin_amdgcn_s_sleep(1);
      }
      __syncthreads();
    }
  }
}

// ---------------------------------------------------------------------------
// ce_vt: one block per 128-vocab slice (250 blocks, 512 thr). w_o slice
// resident in LDS for all 47 decoder steps (r12-validated).
// ---------------------------------------------------------------------------
__global__ __launch_bounds__(512,1) void ce_vt_kernel(
    const unsigned short* __restrict__ h2_bf, const unsigned short* __restrict__ wo_bf,
    const float* __restrict__ b_o, const int* __restrict__ ids,
    float* __restrict__ partial, float* __restrict__ tgt)
{
  const int vt = blockIdx.x, v0 = vt*128;
  const int t = threadIdx.x, wv = t>>6, l = t&63, ln = l&15, lk = l>>4;
  __shared__ short8 smB[128*64];   // 128 KB
  __shared__ short8 smAc[64*8];    // 8 KB
  __shared__ float red[8][64];
  __shared__ int tid_s[64];

  for (int i = t; i < 128*64; i += 512){
    int n = i >> 6, c = i & 63;
    smB[n*64 + ((c & 56) | ((c & 7) ^ (n & 7)))] =
        *(const short8*)(wo_bf + (long)(v0+n)*512 + c*8);
  }
  const int nn = wv*16 + ln;
  const float bo = b_o[v0 + nn];
  __syncthreads();

  for (int td = 0; td < 47; ++td){
    if (t < 64) tid_s[t] = ids[t*T_ + td + 1];
    const unsigned short* hp = h2_bf + (long)(49+td)*BH_;

    f32x4 acc[4];
#pragma unroll
    for (int mf=0;mf<4;++mf) acc[mf] = (f32x4){0.f,0.f,0.f,0.f};

    for (int kc=0; kc<8; ++kc){
      __syncthreads();
      { int m = t>>3, c = t&7;
        smAc[m*8 + (c ^ (m&7))] = *(const short8*)(hp + m*512 + kc*64 + c*8); }
      __syncthreads();
#pragma unroll
      for (int ks2=0; ks2<2; ++ks2){
        short8 bfr = smB[nn*64 + kc*8 + ((ks2*4+lk)^(nn&7))];
#pragma unroll
        for (int mf=0; mf<4; ++mf){
          int m = mf*16+ln;
          short8 afr = smAc[m*8 + ((ks2*4+lk)^(m&7))];
          acc[mf] = __builtin_amdgcn_mfma_f32_16x16x32_bf16(afr, bfr, acc[mf], 0,0,0);
        }
      }
    }

    float se[4][4];
#pragma unroll
    for (int mf=0; mf<4; ++mf)
#pragma unroll
      for (int r=0;r<4;++r){
        int m = mf*16 + lk*4 + r;
        float lg = acc[mf][r] + bo;
        se[mf][r] = __expf(lg);
        if (v0 + nn == tid_s[m]) tgt[td*64 + m] = lg;
      }
#pragma unroll
    for (int off=1; off<16; off<<=1)
#pragma unroll
      for (int mf=0; mf<4; ++mf)
#pragma unroll
        for (int r=0;r<4;++r) se[mf][r] += __shfl_xor(se[mf][r], off);
    if (ln == 0){
#pragma unroll
      for (int mf=0; mf<4; ++mf)
        *(f32x4*)&red[wv][mf*16 + lk*4] = (f32x4){se[mf][0],se[mf][1],se[mf][2],se[mf][3]};
    }
    __syncthreads();
    if (t < 64){
      float ssum = 0.f;
#pragma unroll
      for (int w2=0; w2<8; ++w2) ssum += red[w2][t];
      partial[(long)vt*3008 + td*64 + t] = ssum;
    }
  }
}

__global__ void ce_combine(const float* __restrict__ partial, const float* __restrict__ tgt,
                           float* __restrict__ ce_row){
  int r = blockIdx.x*256 + threadIdx.x;
  if (r < 3008){
    float s = 0.f;
    for (int i=0;i<250;++i) s += partial[(long)i*3008 + r];
    ce_row[r] = __logf(s) - tgt[r];
  }
}

__global__ void ce_final(const float* __restrict__ ce_row, float* __restrict__ out){
  __shared__ float red[256];
  float s = 0.f;
  for (int i=threadIdx.x; i<3008; i+=256) s += ce_row[i];
  red[threadIdx.x] = s;
  __syncthreads();
  for (int off=128; off>0; off>>=1){
    if (threadIdx.x < off) red[threadIdx.x] += red[threadIdx.x + off];
    __syncthreads();
  }
  if (threadIdx.x == 0) out[0] = red[0] * (1.0f/4096.0f);
}

// ---------------------------------------------------------------------------
extern "C" void kernel_launch(void* const* d_in, const int* in_sizes, int n_in,
                              void* d_out, int out_size, void* d_ws, size_t ws_size,
                              hipStream_t stream)
{
  (void)in_sizes; (void)n_in; (void)out_size; (void)ws_size;
  const float* feat    = (const float*)d_in[0];
  const float* caption = (const float*)d_in[1];
  const int*   ids     = (const int*)d_in[2];
  const float* w_ih1  = (const float*)d_in[3];
  const float* w_hh1  = (const float*)d_in[4];
  const float* b_ih1  = (const float*)d_in[5];
  const float* b_hh1  = (const float*)d_in[6];
  const float* w_ih2  = (const float*)d_in[7];
  const float* w_hh2  = (const float*)d_in[8];
  const float* b_ih2  = (const float*)d_in[9];
  const float* b_hh2  = (const float*)d_in[10];
  const float* w_hhd1 = (const float*)d_in[12];
  const float* b_ihd1 = (const float*)d_in[13];
  const float* b_hhd1 = (const float*)d_in[14];
  const float* w_ihd2 = (const float*)d_in[15];
  const float* w_hhd2 = (const float*)d_in[16];
  const float* b_ihd2 = (const float*)d_in[17];
  const float* b_hhd2 = (const float*)d_in[18];
  const float* w_o    = (const float*)d_in[19];
  const float* b_o    = (const float*)d_in[20];

  char* p = (char*)d_ws;
  unsigned short* h1    = (unsigned short*)p; p += 96L*BH_*2;
  unsigned short* h2    = (unsigned short*)p; p += 96L*BH_*2;
  unsigned short* w1e   = (unsigned short*)p; p += 2048L*512*2;
  unsigned short* w1d   = (unsigned short*)p; p += 2048L*512*2;
  unsigned short* w2e   = (unsigned short*)p; p += 2048L*1024*2;
  unsigned short* w2d   = (unsigned short*)p; p += 2048L*1024*2;
  unsigned short* wx1   = (unsigned short*)p; p += 2048L*512*2;
  unsigned short* wcap  = (unsigned short*)p; p += 2048L*512*2;
  unsigned short* x1b   = (unsigned short*)p; p += 48L*BG_*2;
  unsigned short* capqb = (unsigned short*)p; p += 47L*BG_*2;
  unsigned short* wo_bf = (unsigned short*)p; p += 32000L*512*2;
  float* bd1s  = (float*)p; p += 2048*4;
  float* b2es  = (float*)p; p += 2048*4;
  float* partial = (float*)p; p += 250L*3008*4;
  float* tgt   = (float*)p; p += 3008*4;
  float* ce_row= (float*)p; p += 3008*4;
  unsigned* flags = (unsigned*)p; p += 4096*4;

  prep_kernel<<<1024, 256, 0, stream>>>(
      w_hh1, w_hhd1, w_hh2, w_ih2, w_hhd2, w_ihd2, w_ih1, w_o,
      b_ihd1, b_hhd1, b_ih2, b_hh2,
      w1e, w1d, w2e, w2d, wx1, wcap, wo_bf, bd1s, b2es, h1, h2, flags);

  mm_pre2_kernel<<<dim3(95,8), 512, 0, stream>>>(
      feat, caption, wx1, wcap, b_ih1, b_hh1, b_ihd2, b_hhd2, x1b, capqb);

  // merged two-layer chain: 32 blocks, 32-participant barrier
  chain_kernel<<<32, 256, 0, stream>>>(
      w1e, w1d, w2e, w2d, x1b, capqb, bd1s, b2es, h1, h2, flags);

  ce_vt_kernel<<<250, 512, 0, stream>>>(h2, wo_bf, b_o, ids, partial, tgt);
  ce_combine<<<12, 256, 0, stream>>>(partial, tgt, ce_row);
  ce_final<<<1, 256, 0, stream>>>(ce_row, (float*)d_out);
}